// Round 2
// baseline (964.236 us; speedup 1.0000x reference)
//
#include <hip/hip_runtime.h>
#include <hip/hip_bf16.h>
#include <math.h>

// Fused decoder + cross-entropy on MI355X.
//   logits = x @ W^T  (4096 x 50257, K=1024), loss = mean(-log_softmax(logits)[y])
// Plan: bf16-cast x/W once (W LLC-resident), MFMA GEMM (m97 structure) with fused
// online-softmax partial stats per 128-wide vocab tile, fp32 dot for target logit,
// then logsumexp-combine + mean. Never materializes the 823MB logits matrix.
//
// R1: resubmission — two GPUAcquisitionTimeouts, no counter data yet; no
// evidence-based edits to make. Next planned lever once baseline counters
// exist: 256-square 8-phase K-loop port (T3+T4, predicted +1.7x on GEMM).

#define N_NODES 4096
#define D_EMB   1024
#define VOCAB   50257
#define VPAD    50304   // 393 * 128, zero-padded W rows (masked in epilogue)
#define NT      393     // number of 128-wide vocab tiles

typedef __attribute__((ext_vector_type(8))) short short8;   // 8 bf16 = 4 VGPRs (MFMA A/B frag)
typedef __attribute__((ext_vector_type(4))) float f32x4;    // MFMA C/D frag

__device__ __forceinline__ unsigned short f2bf(float f) {
  // round-to-nearest-even fp32 -> bf16
  unsigned int x = __float_as_uint(f);
  x += 0x7fffu + ((x >> 16) & 1u);
  return (unsigned short)(x >> 16);
}

// ---------------- fp32 -> bf16 conversion (W padded to VPAD rows) ---------------
__global__ void cvt_w_kernel(const float* __restrict__ W, unsigned short* __restrict__ Wb) {
  long long gid = (long long)blockIdx.x * 256 + threadIdx.x;  // one 8-elem group per thread
  long long e = gid << 3;
  int row = (int)(e >> 10);   // / D_EMB
  short8 o;
  if (row < VOCAB) {
    const float4* p = (const float4*)(W + e);
    float4 u = p[0];
    float4 v = p[1];
    o[0] = (short)f2bf(u.x); o[1] = (short)f2bf(u.y); o[2] = (short)f2bf(u.z); o[3] = (short)f2bf(u.w);
    o[4] = (short)f2bf(v.x); o[5] = (short)f2bf(v.y); o[6] = (short)f2bf(v.z); o[7] = (short)f2bf(v.w);
  } else {
    o[0]=0; o[1]=0; o[2]=0; o[3]=0; o[4]=0; o[5]=0; o[6]=0; o[7]=0;
  }
  *(short8*)(Wb + e) = o;
}

__global__ void cvt_x_kernel(const float* __restrict__ x, unsigned short* __restrict__ Xb) {
  long long gid = (long long)blockIdx.x * 256 + threadIdx.x;
  long long e = gid << 3;
  const float4* p = (const float4*)(x + e);
  float4 u = p[0];
  float4 v = p[1];
  short8 o;
  o[0] = (short)f2bf(u.x); o[1] = (short)f2bf(u.y); o[2] = (short)f2bf(u.z); o[3] = (short)f2bf(u.w);
  o[4] = (short)f2bf(v.x); o[5] = (short)f2bf(v.y); o[6] = (short)f2bf(v.z); o[7] = (short)f2bf(v.w);
  *(short8*)(Xb + e) = o;
}

// ---------------- target logit in full fp32: logit_y[n] = x_n . W_{y[n]} -------
__global__ void dot_y_kernel(const float* __restrict__ x, const float* __restrict__ W,
                             const int* __restrict__ y, float* __restrict__ logit_y) {
  __shared__ float red[4];
  const int n = blockIdx.x;
  const int t = threadIdx.x;
  const int lbl = y[n];
  const float* xr = x + ((long long)n << 10);
  const float* wr = W + ((long long)lbl << 10);
  float s = 0.f;
  #pragma unroll
  for (int i = 0; i < 4; ++i) {
    int k = t + i * 256;
    s = fmaf(xr[k], wr[k], s);
  }
  #pragma unroll
  for (int m = 32; m; m >>= 1) s += __shfl_xor(s, m, 64);
  if ((t & 63) == 0) red[t >> 6] = s;
  __syncthreads();
  if (t == 0) logit_y[n] = red[0] + red[1] + red[2] + red[3];
}

// ---------------- bf16 MFMA GEMM (128x128 tile, BK=64) + fused softmax stats ----
// m97 structure: global_load_lds width=16 staging, 2 barriers / K-step,
// 4 waves in 2x2 layout, each wave owns a 64x64 output subtile (4x4 MFMA frags).
// Deliberate non-fixes (measured NULL in this 2-phase regime): LDS read
// bank conflicts (T2 gate, m228d), XCD swizzle (L3-fit, m160), setprio (m190).
__global__ __launch_bounds__(256) void gemm_stats_kernel(
    const unsigned short* __restrict__ Xb,
    const unsigned short* __restrict__ Wb,
    float2* __restrict__ partials)  // [NT][N_NODES]: (rowmax, sumexp) per vocab tile
{
  __shared__ unsigned short As[128 * 64];   // 16 KB, linear (global_load_lds needs linear)
  __shared__ unsigned short Bs[128 * 64];   // 16 KB
  __shared__ float2 stats[128][2];          // per-row (max, sum) for each wave-column half

  const int tid  = threadIdx.x;
  const int lane = tid & 63;
  const int wid  = tid >> 6;
  const int wr   = wid >> 1;    // wave row  (0..1) -> rows  wr*64..
  const int wc   = wid & 1;     // wave col  (0..1) -> cols  wc*64..
  const int g    = lane >> 4;   // 4-lane-group id (0..3)
  const int r16  = lane & 15;

  const int rowTile = blockIdx.x;   // 0..31  (XCD = rowTile % 8 -> A-tiles L2-resident)
  const int vocTile = blockIdx.y;   // 0..392 (W-tiles stream through L3)

  const long long abase = (long long)rowTile * 128 * D_EMB;
  const long long bbase = (long long)vocTile * 128 * D_EMB;

  f32x4 acc[4][4];
  #pragma unroll
  for (int m = 0; m < 4; ++m)
    #pragma unroll
    for (int n = 0; n < 4; ++n)
      #pragma unroll
      for (int j = 0; j < 4; ++j)
        acc[m][n][j] = 0.f;

  const int kk_st  = (tid & 7) << 3;  // k offset of this thread's 16B staging chunk
  const int row_st = tid >> 3;        // base row of this thread's staging chunk

  for (int k0 = 0; k0 < D_EMB; k0 += 64) {
    if (k0) __syncthreads();   // previous compute done before overwriting LDS
    #pragma unroll
    for (int it = 0; it < 4; ++it) {
      const int idx = it * 256 + tid;       // 0..1023: 16B chunk index in tile
      const int row = it * 32 + row_st;     // 0..127
      const unsigned short* ga = Xb + abase + (long long)row * D_EMB + k0 + kk_st;
      const unsigned short* gb = Wb + bbase + (long long)row * D_EMB + k0 + kk_st;
      __builtin_amdgcn_global_load_lds((const __attribute__((address_space(1))) void*)ga,
                                       (__attribute__((address_space(3))) void*)(As + idx * 8),
                                       16, 0, 0);
      __builtin_amdgcn_global_load_lds((const __attribute__((address_space(1))) void*)gb,
                                       (__attribute__((address_space(3))) void*)(Bs + idx * 8),
                                       16, 0, 0);
    }
    __syncthreads();  // compiler emits vmcnt(0) drain before s_barrier

    // LDS -> fragments: A row = wr*64+m*16+(lane&15), k = kk*32+(lane>>4)*8 (contiguous 8)
    short8 a[4][2], b[4][2];
    #pragma unroll
    for (int m = 0; m < 4; ++m)
      #pragma unroll
      for (int kk = 0; kk < 2; ++kk)
        a[m][kk] = *(const short8*)(As + (wr * 64 + m * 16 + r16) * 64 + kk * 32 + g * 8);
    #pragma unroll
    for (int n = 0; n < 4; ++n)
      #pragma unroll
      for (int kk = 0; kk < 2; ++kk)
        b[n][kk] = *(const short8*)(Bs + (wc * 64 + n * 16 + r16) * 64 + kk * 32 + g * 8);

    #pragma unroll
    for (int m = 0; m < 4; ++m)
      #pragma unroll
      for (int n = 0; n < 4; ++n) {
        acc[m][n] = __builtin_amdgcn_mfma_f32_16x16x32_bf16(a[m][0], b[n][0], acc[m][n], 0, 0, 0);
        acc[m][n] = __builtin_amdgcn_mfma_f32_16x16x32_bf16(a[m][1], b[n][1], acc[m][n], 0, 0, 0);
      }
  }

  // ---- fused epilogue: per-row max & sum(exp) over this block's 128 vocab cols ----
  // C/D layout: col = n*16 + (lane&15), row = m*16 + (lane>>4)*4 + j   [m89/m91]
  const int colbase = vocTile * 128 + wc * 64;
  #pragma unroll
  for (int m = 0; m < 4; ++m) {
    #pragma unroll
    for (int j = 0; j < 4; ++j) {
      float vmax = -INFINITY;
      #pragma unroll
      for (int n = 0; n < 4; ++n) {
        const int colg = colbase + n * 16 + r16;
        float v = (colg < VOCAB) ? acc[m][n][j] : -INFINITY;
        vmax = fmaxf(vmax, v);
      }
      // row values live in the 16 lanes sharing (lane>>4); xor masks <16 stay in-group
      vmax = fmaxf(vmax, __shfl_xor(vmax, 1));
      vmax = fmaxf(vmax, __shfl_xor(vmax, 2));
      vmax = fmaxf(vmax, __shfl_xor(vmax, 4));
      vmax = fmaxf(vmax, __shfl_xor(vmax, 8));
      float ssum = 0.f;
      #pragma unroll
      for (int n = 0; n < 4; ++n) {
        const int colg = colbase + n * 16 + r16;
        if (colg < VOCAB) ssum += __expf(acc[m][n][j] - vmax);
      }
      ssum += __shfl_xor(ssum, 1);
      ssum += __shfl_xor(ssum, 2);
      ssum += __shfl_xor(ssum, 4);
      ssum += __shfl_xor(ssum, 8);
      if (r16 == 0) {
        const int rloc = wr * 64 + m * 16 + g * 4 + j;
        stats[rloc][wc] = make_float2(vmax, ssum);
      }
    }
  }
  __syncthreads();
  if (tid < 128) {
    float2 p0 = stats[tid][0];
    float2 p1 = stats[tid][1];
    float M = fmaxf(p0.x, p1.x);
    float S = p0.y * __expf(p0.x - M) + p1.y * __expf(p1.x - M);
    partials[(long long)vocTile * N_NODES + rowTile * 128 + tid] = make_float2(M, S);
  }
}

// ---------------- per-row logsumexp over NT tiles, then nll ---------------------
__global__ void lse_kernel(const float2* __restrict__ partials,
                           const float* __restrict__ logit_y,
                           float* __restrict__ row_nll) {
  const int n = blockIdx.x * 256 + threadIdx.x;   // 4096 threads total
  float M = -INFINITY, S = 0.f;
  for (int t = 0; t < NT; ++t) {
    float2 p = partials[(long long)t * N_NODES + n];  // coalesced across threads
    float newM = fmaxf(M, p.x);
    S = S * __expf(M - newM) + p.y * __expf(p.x - newM);
    M = newM;
  }
  row_nll[n] = (M + logf(S)) - logit_y[n];
}

__global__ void mean_kernel(const float* __restrict__ row_nll, float* __restrict__ out) {
  __shared__ float red[4];
  float s = 0.f;
  for (int i = threadIdx.x; i < N_NODES; i += 256) s += row_nll[i];
  #pragma unroll
  for (int m = 32; m; m >>= 1) s += __shfl_xor(s, m, 64);
  if ((threadIdx.x & 63) == 0) red[threadIdx.x >> 6] = s;
  __syncthreads();
  if (threadIdx.x == 0) out[0] = (red[0] + red[1] + red[2] + red[3]) * (1.0f / N_NODES);
}

// ---------------- launcher ------------------------------------------------------
extern "C" void kernel_launch(void* const* d_in, const int* in_sizes, int n_in,
                              void* d_out, int out_size, void* d_ws, size_t ws_size,
                              hipStream_t stream) {
  const float* x = (const float*)d_in[0];
  const float* W = (const float*)d_in[1];
  const int*   y = (const int*)d_in[2];   // harness: integer -> const int*
  float* out = (float*)d_out;

  // ws layout (all 256B-aligned offsets), total 124,321,792 bytes
  char* ws = (char*)d_ws;
  unsigned short* Wb = (unsigned short*)ws;                 // VPAD*D*2   = 103,022,592
  unsigned short* Xb = (unsigned short*)(ws + 103022592);   // N*D*2      =   8,388,608
  float2* partials   = (float2*)(ws + 111411200);           // NT*N*8     =  12,877,824
  float* logit_y     = (float*)(ws + 124289024);            // N*4        =      16,384
  float* row_nll     = (float*)(ws + 124305408);            // N*4        =      16,384

  hipLaunchKernelGGL(cvt_w_kernel, dim3(VPAD * (D_EMB / 8) / 256), dim3(256), 0, stream, W, Wb);
  hipLaunchKernelGGL(cvt_x_kernel, dim3(N_NODES * (D_EMB / 8) / 256), dim3(256), 0, stream, x, Xb);
  hipLaunchKernelGGL(dot_y_kernel, dim3(N_NODES), dim3(256), 0, stream, x, W, y, logit_y);
  // gridDim.x = row tiles (fast-varying): 32 consecutive blocks share one W-tile -> L2 reuse
  hipLaunchKernelGGL(gemm_stats_kernel, dim3(32, NT), dim3(256), 0, stream, Xb, Wb, partials);
  hipLaunchKernelGGL(lse_kernel, dim3(N_NODES / 256), dim3(256), 0, stream, partials, logit_y, row_nll);
  hipLaunchKernelGGL(mean_kernel, dim3(1), dim3(256), 0, stream, row_nll, out);
}

// Round 3
// 803.650 us; speedup vs baseline: 1.1998x; 1.1998x over previous
//
#include <hip/hip_runtime.h>
#include <hip/hip_bf16.h>
#include <math.h>

// Fused decoder + cross-entropy on MI355X.
//   logits = x @ W^T  (4096 x 50257, K=1024), loss = mean(-log_softmax(logits)[y])
// R3: GEMM ported to 256^2 tile, 8-wave, quadrant-phased K-loop with counted
// vmcnt(8) + raw s_barrier (T3+T4), LDS XOR-swizzle (T2, both-sides involution),
// setprio around MFMA clusters (T5). lse rewritten wave-per-row with
// [node][tile] partials layout. R2 baseline: 964 us total, gemm 690 us
// (MfmaUtil 26% = 2-phase structural limit), lse ~150-200 us (16 blocks only).

#define N_NODES 4096
#define D_EMB   1024
#define VOCAB   50257
#define VPAD    50432   // 197 * 256, zero-padded W rows (masked in epilogue)
#define NT      197     // number of 256-wide vocab tiles
#define KT      16      // K-tiles of 64 (1024/64)

typedef __attribute__((ext_vector_type(8))) short short8;   // 8 bf16 (MFMA A/B frag)
typedef __attribute__((ext_vector_type(4))) float f32x4;    // MFMA C/D frag

__device__ __forceinline__ unsigned short f2bf(float f) {
  unsigned int x = __float_as_uint(f);
  x += 0x7fffu + ((x >> 16) & 1u);
  return (unsigned short)(x >> 16);
}

// ---------------- fp32 -> bf16 conversion (W padded to VPAD rows) ---------------
__global__ void cvt_w_kernel(const float* __restrict__ W, unsigned short* __restrict__ Wb) {
  long long gid = (long long)blockIdx.x * 256 + threadIdx.x;
  long long e = gid << 3;
  int row = (int)(e >> 10);
  short8 o;
  if (row < VOCAB) {
    const float4* p = (const float4*)(W + e);
    float4 u = p[0];
    float4 v = p[1];
    o[0] = (short)f2bf(u.x); o[1] = (short)f2bf(u.y); o[2] = (short)f2bf(u.z); o[3] = (short)f2bf(u.w);
    o[4] = (short)f2bf(v.x); o[5] = (short)f2bf(v.y); o[6] = (short)f2bf(v.z); o[7] = (short)f2bf(v.w);
  } else {
    o[0]=0; o[1]=0; o[2]=0; o[3]=0; o[4]=0; o[5]=0; o[6]=0; o[7]=0;
  }
  *(short8*)(Wb + e) = o;
}

__global__ void cvt_x_kernel(const float* __restrict__ x, unsigned short* __restrict__ Xb) {
  long long gid = (long long)blockIdx.x * 256 + threadIdx.x;
  long long e = gid << 3;
  const float4* p = (const float4*)(x + e);
  float4 u = p[0];
  float4 v = p[1];
  short8 o;
  o[0] = (short)f2bf(u.x); o[1] = (short)f2bf(u.y); o[2] = (short)f2bf(u.z); o[3] = (short)f2bf(u.w);
  o[4] = (short)f2bf(v.x); o[5] = (short)f2bf(v.y); o[6] = (short)f2bf(v.z); o[7] = (short)f2bf(v.w);
  *(short8*)(Xb + e) = o;
}

// ---------------- target logit in full fp32 ------------------------------------
__global__ void dot_y_kernel(const float* __restrict__ x, const float* __restrict__ W,
                             const int* __restrict__ y, float* __restrict__ logit_y) {
  __shared__ float red[4];
  const int n = blockIdx.x;
  const int t = threadIdx.x;
  const int lbl = y[n];
  const float* xr = x + ((long long)n << 10);
  const float* wr = W + ((long long)lbl << 10);
  float s = 0.f;
  #pragma unroll
  for (int i = 0; i < 4; ++i) {
    int k = t + i * 256;
    s = fmaf(xr[k], wr[k], s);
  }
  #pragma unroll
  for (int m = 32; m; m >>= 1) s += __shfl_xor(s, m, 64);
  if ((t & 63) == 0) red[t >> 6] = s;
  __syncthreads();
  if (t == 0) logit_y[n] = red[0] + red[1] + red[2] + red[3];
}

// ---------------- 256^2 MFMA GEMM, counted-vmcnt phased K-loop ------------------
// 8 waves (2 row x 4 col), per-wave output 128x64 (acc[8][4]).
// LDS: 2 buffers x (A 256x64 + B 256x64) bf16 = 128 KB. XOR-swizzle:
//   slot(r,c) holds element (r, c ^ ((r&7)<<3))  [elements; = byte<<4 swizzle]
//   Both stage-source and ds_read apply the same involution (rule #21).
// Schedule per K-tile u (buffer b=u&1):
//   ds_read b(8)+aQ0(4)+aQ1(4); MFMA Q0; read aQ2; MFMA Q1; read aQ3; MFMA Q2;
//   lgkmcnt(0); s_barrier;            // all waves' reads of buf b drained
//   STAGE(u+2 -> buf b) (8 gload_lds); MFMA Q3;
//   vmcnt(8); s_barrier;              // u+1's loads (issued at u-1) landed
// vmcnt never drains to 0 in steady state (T4); raw s_barrier avoids the
// compiler's vmcnt(0)-before-__syncthreads drain (the m97 ~900TF ceiling).
#define MFMAQ(Q, AF)                                                                  \
  do {                                                                                \
    _Pragma("unroll")                                                                 \
    for (int ni = 0; ni < 4; ++ni) {                                                  \
      _Pragma("unroll")                                                               \
      for (int kk = 0; kk < 2; ++kk) {                                                \
        acc[2*(Q)  ][ni] = __builtin_amdgcn_mfma_f32_16x16x32_bf16(AF[0][kk], bf[ni][kk], acc[2*(Q)  ][ni], 0, 0, 0); \
        acc[2*(Q)+1][ni] = __builtin_amdgcn_mfma_f32_16x16x32_bf16(AF[1][kk], bf[ni][kk], acc[2*(Q)+1][ni], 0, 0, 0); \
      }                                                                               \
    }                                                                                 \
  } while (0)

#define STAGE(U)                                                                      \
  do {                                                                                \
    const int _b = (U) & 1;                                                           \
    const long long _ko = (long long)(U) * 64;                                        \
    _Pragma("unroll")                                                                 \
    for (int h = 0; h < 2; ++h) {                                                     \
      _Pragma("unroll")                                                               \
      for (int p = 0; p < 2; ++p) {                                                   \
        __builtin_amdgcn_global_load_lds(                                             \
            (const __attribute__((address_space(1))) void*)(Xb + abase[h][p] + _ko),  \
            (__attribute__((address_space(3))) void*)(sh + _b*32768 + h*8192 + p*4096 + dst0), \
            16, 0, 0);                                                                \
      }                                                                               \
    }                                                                                 \
    _Pragma("unroll")                                                                 \
    for (int h = 0; h < 2; ++h) {                                                     \
      _Pragma("unroll")                                                               \
      for (int p = 0; p < 2; ++p) {                                                   \
        __builtin_amdgcn_global_load_lds(                                             \
            (const __attribute__((address_space(1))) void*)(Wb + bbase[h][p] + _ko),  \
            (__attribute__((address_space(3))) void*)(sh + _b*32768 + 16384 + h*8192 + p*4096 + dst0), \
            16, 0, 0);                                                                \
      }                                                                               \
    }                                                                                 \
  } while (0)

__global__ __launch_bounds__(512, 2) void gemm_stats_kernel(
    const unsigned short* __restrict__ Xb,
    const unsigned short* __restrict__ Wb,
    float2* __restrict__ partials)  // [N_NODES][NT]: (rowmax, sumexp) per vocab tile
{
  __shared__ __align__(16) unsigned short sh[65536];  // 128 KB

  const int tid  = threadIdx.x;
  const int lane = tid & 63;
  const int wid  = tid >> 6;    // 0..7
  const int wr   = wid >> 2;    // 0..1: rows wr*128..
  const int wcol = wid & 3;     // 0..3: cols wcol*64..
  const int g    = lane >> 4;   // 0..3
  const int r16  = lane & 15;

  const int bm0 = blockIdx.x * 256;
  const int bn0 = blockIdx.y * 256;

  // --- staging geometry: thread t stages linear 16B slot (pass p): row p*64+(t>>3),
  //     col (t&7)*8; source col is XOR-swizzled (involution) so reads can swizzle.
  const int srb = tid >> 3;                              // 0..63
  const int scg = ((tid & 7) << 3) ^ ((srb & 7) << 3);   // pre-swizzled source col
  const int dst0 = tid * 8;                              // elements within a pass
  long long abase[2][2], bbase[2][2];
  #pragma unroll
  for (int h = 0; h < 2; ++h)
    #pragma unroll
    for (int p = 0; p < 2; ++p) {
      abase[h][p] = (long long)(bm0 + h*128 + p*64 + srb) * D_EMB + scg;
      bbase[h][p] = (long long)(bn0 + h*128 + p*64 + srb) * D_EMB + scg;
    }

  f32x4 acc[8][4];
  #pragma unroll
  for (int m = 0; m < 8; ++m)
    #pragma unroll
    for (int n = 0; n < 4; ++n)
      #pragma unroll
      for (int j = 0; j < 4; ++j)
        acc[m][n][j] = 0.f;

  // --- fragment-read geometry (swizzled) ---
  const int arow = wr * 128 + r16;   // + mi*16
  const int brow = wcol * 64 + r16;  // + ni*16
  const int sw   = (r16 & 7) << 3;
  const int colp0 = (g * 8) ^ sw;
  const int colp1 = (32 + g * 8) ^ sw;

  // --- prologue: stage K-tiles 0 (buf0) and 1 (buf1); require 0 landed ---
  STAGE(0);
  STAGE(1);
  asm volatile("s_waitcnt vmcnt(8)" ::: "memory");
  __builtin_amdgcn_s_barrier();

  for (int u = 0; u < KT; ++u) {
    const unsigned short* Ab = sh + (u & 1) * 32768;
    const unsigned short* Bb = Ab + 16384;

    short8 bf[4][2], aA[2][2], aB[2][2];
    #pragma unroll
    for (int ni = 0; ni < 4; ++ni) {
      bf[ni][0] = *(const short8*)(Bb + (brow + ni*16)*64 + colp0);
      bf[ni][1] = *(const short8*)(Bb + (brow + ni*16)*64 + colp1);
    }
    #pragma unroll
    for (int i = 0; i < 2; ++i) {
      aA[i][0] = *(const short8*)(Ab + (arow + i*16)*64 + colp0);
      aA[i][1] = *(const short8*)(Ab + (arow + i*16)*64 + colp1);
      aB[i][0] = *(const short8*)(Ab + (arow + (2+i)*16)*64 + colp0);
      aB[i][1] = *(const short8*)(Ab + (arow + (2+i)*16)*64 + colp1);
    }

    __builtin_amdgcn_s_setprio(1);
    MFMAQ(0, aA);
    __builtin_amdgcn_s_setprio(0);

    #pragma unroll
    for (int i = 0; i < 2; ++i) {   // quadrant 2 a-frags
      aA[i][0] = *(const short8*)(Ab + (arow + (4+i)*16)*64 + colp0);
      aA[i][1] = *(const short8*)(Ab + (arow + (4+i)*16)*64 + colp1);
    }
    __builtin_amdgcn_s_setprio(1);
    MFMAQ(1, aB);
    __builtin_amdgcn_s_setprio(0);

    #pragma unroll
    for (int i = 0; i < 2; ++i) {   // quadrant 3 a-frags
      aB[i][0] = *(const short8*)(Ab + (arow + (6+i)*16)*64 + colp0);
      aB[i][1] = *(const short8*)(Ab + (arow + (6+i)*16)*64 + colp1);
    }
    __builtin_amdgcn_s_setprio(1);
    MFMAQ(2, aA);
    __builtin_amdgcn_s_setprio(0);

    // all of this wave's ds_reads of buf b complete, then all waves rendezvous
    asm volatile("s_waitcnt lgkmcnt(0)" ::: "memory");
    __builtin_amdgcn_s_barrier();

    if (u < KT - 2) STAGE(u + 2);   // restage this buffer for K-tile u+2

    __builtin_amdgcn_s_setprio(1);
    MFMAQ(3, aB);
    __builtin_amdgcn_s_setprio(0);

    if (u < KT - 2) {
      asm volatile("s_waitcnt vmcnt(8)" ::: "memory");  // u+1's 8 loads landed
      __builtin_amdgcn_s_barrier();
    } else if (u == KT - 2) {
      asm volatile("s_waitcnt vmcnt(0)" ::: "memory");  // tail drain (once)
      __builtin_amdgcn_s_barrier();
    }
  }

  // ---- fused epilogue: per-row max & sum(exp) over this block's 256 vocab cols ----
  // C/D layout: col = ni*16 + r16, row = mi*16 + g*4 + j
  // stats aliases buf0's A region (last K-tile read buf1 only) -> safe pre-barrier.
  float2 (*stats)[4] = (float2 (*)[4])sh;   // [256][4], 8 KB
  #pragma unroll
  for (int mi = 0; mi < 8; ++mi) {
    #pragma unroll
    for (int j = 0; j < 4; ++j) {
      float vmax = -INFINITY;
      #pragma unroll
      for (int ni = 0; ni < 4; ++ni) {
        const int colg = bn0 + wcol*64 + ni*16 + r16;
        float v = (colg < VOCAB) ? acc[mi][ni][j] : -INFINITY;
        vmax = fmaxf(vmax, v);
      }
      vmax = fmaxf(vmax, __shfl_xor(vmax, 1));
      vmax = fmaxf(vmax, __shfl_xor(vmax, 2));
      vmax = fmaxf(vmax, __shfl_xor(vmax, 4));
      vmax = fmaxf(vmax, __shfl_xor(vmax, 8));
      float ssum = 0.f;
      #pragma unroll
      for (int ni = 0; ni < 4; ++ni) {
        const int colg = bn0 + wcol*64 + ni*16 + r16;
        if (colg < VOCAB) ssum += __expf(acc[mi][ni][j] - vmax);
      }
      ssum += __shfl_xor(ssum, 1);
      ssum += __shfl_xor(ssum, 2);
      ssum += __shfl_xor(ssum, 4);
      ssum += __shfl_xor(ssum, 8);
      if (r16 == 0) {
        stats[wr*128 + mi*16 + g*4 + j][wcol] = make_float2(vmax, ssum);
      }
    }
  }
  __syncthreads();
  if (tid < 256) {
    float2 a0 = stats[tid][0], a1 = stats[tid][1], a2 = stats[tid][2], a3 = stats[tid][3];
    float M = fmaxf(fmaxf(a0.x, a1.x), fmaxf(a2.x, a3.x));
    float S = a0.y * __expf(a0.x - M) + a1.y * __expf(a1.x - M)
            + a2.y * __expf(a2.x - M) + a3.y * __expf(a3.x - M);
    partials[(long long)(bm0 + tid) * NT + blockIdx.y] = make_float2(M, S);
  }
}

// ---------------- per-row logsumexp: one wave per row (coalesced [node][tile]) --
__global__ void lse_kernel(const float2* __restrict__ partials,
                           const float* __restrict__ logit_y,
                           float* __restrict__ row_nll) {
  const int n = blockIdx.x * 4 + (threadIdx.x >> 6);   // 1024 blocks x 4 waves = 4096 rows
  const int l = threadIdx.x & 63;
  const float2* pr = partials + (long long)n * NT;
  float M = -INFINITY, S = 0.f;
  for (int t = l; t < NT; t += 64) {
    float2 p = pr[t];
    float nM = fmaxf(M, p.x);
    S = S * __expf(M - nM) + p.y * __expf(p.x - nM);
    M = nM;
  }
  #pragma unroll
  for (int off = 1; off < 64; off <<= 1) {
    float Mo = __shfl_xor(M, off);
    float So = __shfl_xor(S, off);
    float nM = fmaxf(M, Mo);
    S = S * __expf(M - nM) + So * __expf(Mo - nM);
    M = nM;
  }
  if (l == 0) row_nll[n] = (M + logf(S)) - logit_y[n];
}

__global__ void mean_kernel(const float* __restrict__ row_nll, float* __restrict__ out) {
  __shared__ float red[4];
  float s = 0.f;
  for (int i = threadIdx.x; i < N_NODES; i += 256) s += row_nll[i];
  #pragma unroll
  for (int m = 32; m; m >>= 1) s += __shfl_xor(s, m, 64);
  if ((threadIdx.x & 63) == 0) red[threadIdx.x >> 6] = s;
  __syncthreads();
  if (threadIdx.x == 0) out[0] = (red[0] + red[1] + red[2] + red[3]) * (1.0f / N_NODES);
}

// ---------------- launcher ------------------------------------------------------
extern "C" void kernel_launch(void* const* d_in, const int* in_sizes, int n_in,
                              void* d_out, int out_size, void* d_ws, size_t ws_size,
                              hipStream_t stream) {
  const float* x = (const float*)d_in[0];
  const float* W = (const float*)d_in[1];
  const int*   y = (const int*)d_in[2];
  float* out = (float*)d_out;

  // ws layout (256B-aligned), total 118,161,408 bytes
  char* ws = (char*)d_ws;
  unsigned short* Wb = (unsigned short*)ws;                 // VPAD*D*2 = 103,284,736
  unsigned short* Xb = (unsigned short*)(ws + 103284736);   // N*D*2    =   8,388,608
  float2* partials   = (float2*)(ws + 111673344);           // N*NT*8   =   6,455,296
  float* logit_y     = (float*)(ws + 118128640);            // N*4
  float* row_nll     = (float*)(ws + 118145024);            // N*4

  hipLaunchKernelGGL(cvt_w_kernel, dim3(VPAD * (D_EMB / 8) / 256), dim3(256), 0, stream, W, Wb);
  hipLaunchKernelGGL(cvt_x_kernel, dim3(N_NODES * (D_EMB / 8) / 256), dim3(256), 0, stream, x, Xb);
  hipLaunchKernelGGL(dot_y_kernel, dim3(N_NODES), dim3(256), 0, stream, x, W, y, logit_y);
  hipLaunchKernelGGL(gemm_stats_kernel, dim3(16, NT), dim3(512), 0, stream, Xb, Wb, partials);
  hipLaunchKernelGGL(lse_kernel, dim3(N_NODES / 4), dim3(256), 0, stream, partials, logit_y, row_nll);
  hipLaunchKernelGGL(mean_kernel, dim3(1), dim3(256), 0, stream, row_nll, out);
}

// Round 5
// 796.738 us; speedup vs baseline: 1.2102x; 1.0087x over previous
//
#include <hip/hip_runtime.h>
#include <hip/hip_bf16.h>
#include <math.h>

// Fused decoder + cross-entropy on MI355X.
//   logits = x @ W^T  (4096 x 50257, K=1024), loss = mean(-log_softmax(logits)[y])
// R4/R5: faithful m201 per-phase interleave (4 phases/K-tile, 2 gload_lds + 4-12
// ds_read + 16-MFMA cluster per phase, barriers around MFMA, vmcnt(2) boundary,
// rolling 2/phase staging with race-screened windows). cvt_w grid-stride 2048;
// dot_y fused into lse. History: R2 964us (gemm 690, MfmaUtil 26%, 2-phase
// limit); R3 804us (gemm 552, 33%, coarse split + swizzle: conflicts 1.5e8->1e5);
// R4 not run (GPU acquisition timeout) — resubmitted unchanged.

#define N_NODES 4096
#define D_EMB   1024
#define VOCAB   50257
#define VPAD    50432   // 197 * 256, zero-padded W rows (masked in epilogue)
#define NT      197     // number of 256-wide vocab tiles
#define KT      16      // K-tiles of 64 (1024/64)

typedef __attribute__((ext_vector_type(8))) short short8;   // 8 bf16 (MFMA A/B frag)
typedef __attribute__((ext_vector_type(4))) float f32x4;    // MFMA C/D frag

__device__ __forceinline__ unsigned short f2bf(float f) {
  unsigned int x = __float_as_uint(f);
  x += 0x7fffu + ((x >> 16) & 1u);
  return (unsigned short)(x >> 16);
}

// ---------------- fp32 -> bf16 conversion (W padded; grid-stride 2048) ----------
__global__ void cvt_w_kernel(const float* __restrict__ W, unsigned short* __restrict__ Wb) {
  const long long total = (long long)VPAD * (D_EMB / 8);   // 16B-group count
  for (long long gid = (long long)blockIdx.x * 256 + threadIdx.x; gid < total;
       gid += (long long)gridDim.x * 256) {
    long long e = gid << 3;
    int row = (int)(e >> 10);
    short8 o;
    if (row < VOCAB) {
      const float4* p = (const float4*)(W + e);
      float4 u = p[0];
      float4 v = p[1];
      o[0] = (short)f2bf(u.x); o[1] = (short)f2bf(u.y); o[2] = (short)f2bf(u.z); o[3] = (short)f2bf(u.w);
      o[4] = (short)f2bf(v.x); o[5] = (short)f2bf(v.y); o[6] = (short)f2bf(v.z); o[7] = (short)f2bf(v.w);
    } else {
      o[0]=0; o[1]=0; o[2]=0; o[3]=0; o[4]=0; o[5]=0; o[6]=0; o[7]=0;
    }
    *(short8*)(Wb + e) = o;
  }
}

__global__ void cvt_x_kernel(const float* __restrict__ x, unsigned short* __restrict__ Xb) {
  long long gid = (long long)blockIdx.x * 256 + threadIdx.x;
  long long e = gid << 3;
  const float4* p = (const float4*)(x + e);
  float4 u = p[0];
  float4 v = p[1];
  short8 o;
  o[0] = (short)f2bf(u.x); o[1] = (short)f2bf(u.y); o[2] = (short)f2bf(u.z); o[3] = (short)f2bf(u.w);
  o[4] = (short)f2bf(v.x); o[5] = (short)f2bf(v.y); o[6] = (short)f2bf(v.z); o[7] = (short)f2bf(v.w);
  *(short8*)(Xb + e) = o;
}

// ---------------- 256^2 MFMA GEMM, per-phase interleave (m201 port) -------------
// 8 waves (2 row x 4 col), per-wave output 128x64 (acc[8][4]).
// LDS: buf[b] = A(256x64) + B(256x64) bf16, b=kt&1 -> 128 KB, XOR-swizzled
// (slot(r,c) holds (r, c ^ ((r&7)<<3)); stage-source pre-swizzled, reads swizzle).
// Group u (K-tile u, buf b=u&1), phases q=0..3 (quadrant q = mi 2q,2q+1):
//   q0: ds bf(8)+af(4); stage A-p1(u+1)    | bar | lgk0 | MFMA Q0 | bar
//   q1: ds af(4);       stage B-p0(u+1)    | bar | lgk0 | MFMA Q1 | bar
//   q2: ds af(4);       stage B-p1(u+1), A-p0(u+2) | bar | lgk0 | MFMA Q2 | bar
//   q3: ds af(4);                          | bar | lgk0 | MFMA Q3 | vmcnt(2) | bar
// Race windows verified: A-p1/B-*(u+1) target buf ~b (not read this group);
// A-p0(u+2) targets buf b rows 0..63/half, dead after q1's barrier, staged at q2.
// vmcnt(2) allows only the 2 youngest (A-p0(u+2)) in flight -> kt u+1 fully
// landed (FIFO). Drain-to-0 only at u==KT-2. 8 barriers/K-tile (= m201).
#define MFMAQ(Q)                                                                      \
  do {                                                                                \
    _Pragma("unroll")                                                                 \
    for (int ni = 0; ni < 4; ++ni) {                                                  \
      _Pragma("unroll")                                                               \
      for (int kk = 0; kk < 2; ++kk) {                                                \
        acc[2*(Q)  ][ni] = __builtin_amdgcn_mfma_f32_16x16x32_bf16(af[0][kk], bf[ni][kk], acc[2*(Q)  ][ni], 0, 0, 0); \
        acc[2*(Q)+1][ni] = __builtin_amdgcn_mfma_f32_16x16x32_bf16(af[1][kk], bf[ni][kk], acc[2*(Q)+1][ni], 0, 0, 0); \
      }                                                                               \
    }                                                                                 \
  } while (0)

// stage 2 gload_lds: A or B, K-tile U, row-pair p (rows p*64..p*64+63 per 128-half)
#define STAGE_A(U, P)                                                                 \
  do {                                                                               \
    const int _b = (U) & 1;                                                          \
    const long long _ko = (long long)(U) * 64;                                       \
    _Pragma("unroll")                                                                \
    for (int h = 0; h < 2; ++h)                                                      \
      __builtin_amdgcn_global_load_lds(                                              \
          (const __attribute__((address_space(1))) void*)(Xb + abase[h][P] + _ko),   \
          (__attribute__((address_space(3))) void*)(sh + _b*32768 + h*8192 + (P)*4096 + dst0), \
          16, 0, 0);                                                                 \
  } while (0)
#define STAGE_B(U, P)                                                                 \
  do {                                                                               \
    const int _b = (U) & 1;                                                          \
    const long long _ko = (long long)(U) * 64;                                       \
    _Pragma("unroll")                                                                \
    for (int h = 0; h < 2; ++h)                                                      \
      __builtin_amdgcn_global_load_lds(                                              \
          (const __attribute__((address_space(1))) void*)(Wb + bbase[h][P] + _ko),   \
          (__attribute__((address_space(3))) void*)(sh + _b*32768 + 16384 + h*8192 + (P)*4096 + dst0), \
          16, 0, 0);                                                                 \
  } while (0)

#define PHASE_OPEN()                                   \
  __builtin_amdgcn_s_barrier();                        \
  asm volatile("s_waitcnt lgkmcnt(0)" ::: "memory");   \
  __builtin_amdgcn_sched_barrier(0);                   \
  __builtin_amdgcn_s_setprio(1)
#define PHASE_CLOSE()                                  \
  __builtin_amdgcn_s_setprio(0);                       \
  __builtin_amdgcn_s_barrier()

__global__ __launch_bounds__(512, 2) void gemm_stats_kernel(
    const unsigned short* __restrict__ Xb,
    const unsigned short* __restrict__ Wb,
    float2* __restrict__ partials)  // [N_NODES][NT]: (rowmax, sumexp) per vocab tile
{
  __shared__ __align__(16) unsigned short sh[65536];  // 128 KB

  const int tid  = threadIdx.x;
  const int lane = tid & 63;
  const int wid  = tid >> 6;    // 0..7
  const int wr   = wid >> 2;    // 0..1: rows wr*128..
  const int wcol = wid & 3;     // 0..3: cols wcol*64..
  const int g    = lane >> 4;   // 0..3
  const int r16  = lane & 15;

  const int bm0 = blockIdx.x * 256;
  const int bn0 = blockIdx.y * 256;

  // staging geometry: thread stages 16B at row (h*128+p*64+srb), swizzled col
  const int srb = tid >> 3;                              // 0..63
  const int scg = ((tid & 7) << 3) ^ ((srb & 7) << 3);   // pre-swizzled source col
  const int dst0 = tid * 8;                              // linear elems within 64-row pane
  long long abase[2][2], bbase[2][2];
  #pragma unroll
  for (int h = 0; h < 2; ++h)
    #pragma unroll
    for (int p = 0; p < 2; ++p) {
      abase[h][p] = (long long)(bm0 + h*128 + p*64 + srb) * D_EMB + scg;
      bbase[h][p] = (long long)(bn0 + h*128 + p*64 + srb) * D_EMB + scg;
    }

  f32x4 acc[8][4];
  #pragma unroll
  for (int m = 0; m < 8; ++m)
    #pragma unroll
    for (int n = 0; n < 4; ++n)
      #pragma unroll
      for (int j = 0; j < 4; ++j)
        acc[m][n][j] = 0.f;

  // fragment-read geometry (swizzled)
  const int arow = wr * 128 + r16;   // + mi*16
  const int brow = wcol * 64 + r16;  // + ni*16
  const int sw   = (r16 & 7) << 3;
  const int colp0 = (g * 8) ^ sw;
  const int colp1 = (32 + g * 8) ^ sw;

  // prologue: kt0 full (8 loads) + A-p0(kt1) (2); require kt0 landed
  STAGE_A(0, 0); STAGE_A(0, 1); STAGE_B(0, 0); STAGE_B(0, 1);
  STAGE_A(1, 0);
  asm volatile("s_waitcnt vmcnt(2)" ::: "memory");
  __builtin_amdgcn_s_barrier();

  for (int u = 0; u < KT; ++u) {
    const unsigned short* Ab = sh + (u & 1) * 32768;
    const unsigned short* Bb = Ab + 16384;
    short8 bf[4][2], af[2][2];

    // ---- phase 0: B-frags + Q0 A-frags; stage A-p1(u+1) ----
    #pragma unroll
    for (int ni = 0; ni < 4; ++ni) {
      bf[ni][0] = *(const short8*)(Bb + (brow + ni*16)*64 + colp0);
      bf[ni][1] = *(const short8*)(Bb + (brow + ni*16)*64 + colp1);
    }
    #pragma unroll
    for (int i = 0; i < 2; ++i) {
      af[i][0] = *(const short8*)(Ab + (arow + i*16)*64 + colp0);
      af[i][1] = *(const short8*)(Ab + (arow + i*16)*64 + colp1);
    }
    if (u + 1 < KT) STAGE_A(u + 1, 1);
    PHASE_OPEN();
    MFMAQ(0);
    PHASE_CLOSE();

    // ---- phase 1: Q1 A-frags; stage B-p0(u+1) ----
    #pragma unroll
    for (int i = 0; i < 2; ++i) {
      af[i][0] = *(const short8*)(Ab + (arow + (2+i)*16)*64 + colp0);
      af[i][1] = *(const short8*)(Ab + (arow + (2+i)*16)*64 + colp1);
    }
    if (u + 1 < KT) STAGE_B(u + 1, 0);
    PHASE_OPEN();
    MFMAQ(1);
    PHASE_CLOSE();

    // ---- phase 2: Q2 A-frags; stage B-p1(u+1) then A-p0(u+2) (issue order matters) ----
    #pragma unroll
    for (int i = 0; i < 2; ++i) {
      af[i][0] = *(const short8*)(Ab + (arow + (4+i)*16)*64 + colp0);
      af[i][1] = *(const short8*)(Ab + (arow + (4+i)*16)*64 + colp1);
    }
    if (u + 1 < KT) STAGE_B(u + 1, 1);
    if (u + 2 < KT) STAGE_A(u + 2, 0);
    PHASE_OPEN();
    MFMAQ(2);
    PHASE_CLOSE();

    // ---- phase 3: Q3 A-frags; boundary wait ----
    #pragma unroll
    for (int i = 0; i < 2; ++i) {
      af[i][0] = *(const short8*)(Ab + (arow + (6+i)*16)*64 + colp0);
      af[i][1] = *(const short8*)(Ab + (arow + (6+i)*16)*64 + colp1);
    }
    __builtin_amdgcn_s_barrier();
    asm volatile("s_waitcnt lgkmcnt(0)" ::: "memory");
    __builtin_amdgcn_sched_barrier(0);
    __builtin_amdgcn_s_setprio(1);
    MFMAQ(3);
    __builtin_amdgcn_s_setprio(0);
    if (u < KT - 2) {
      asm volatile("s_waitcnt vmcnt(2)" ::: "memory");  // kt u+1 landed (FIFO)
      __builtin_amdgcn_s_barrier();
    } else if (u == KT - 2) {
      asm volatile("s_waitcnt vmcnt(0)" ::: "memory");  // tail drain (once)
      __builtin_amdgcn_s_barrier();
    }
    // u == KT-1: fall through to epilogue (stats region = buf0 A, last reads buf1)
  }

  // ---- fused epilogue: per-row max & sum(exp) over this block's 256 vocab cols ----
  // C/D layout: col = ni*16 + r16, row = mi*16 + g*4 + j
  float2 (*stats)[4] = (float2 (*)[4])sh;   // [256][4], 8 KB, aliases buf0 A region
  #pragma unroll
  for (int mi = 0; mi < 8; ++mi) {
    #pragma unroll
    for (int j = 0; j < 4; ++j) {
      float vmax = -INFINITY;
      #pragma unroll
      for (int ni = 0; ni < 4; ++ni) {
        const int colg = bn0 + wcol*64 + ni*16 + r16;
        float v = (colg < VOCAB) ? acc[mi][ni][j] : -INFINITY;
        vmax = fmaxf(vmax, v);
      }
      vmax = fmaxf(vmax, __shfl_xor(vmax, 1));
      vmax = fmaxf(vmax, __shfl_xor(vmax, 2));
      vmax = fmaxf(vmax, __shfl_xor(vmax, 4));
      vmax = fmaxf(vmax, __shfl_xor(vmax, 8));
      float ssum = 0.f;
      #pragma unroll
      for (int ni = 0; ni < 4; ++ni) {
        const int colg = bn0 + wcol*64 + ni*16 + r16;
        if (colg < VOCAB) ssum += __expf(acc[mi][ni][j] - vmax);
      }
      ssum += __shfl_xor(ssum, 1);
      ssum += __shfl_xor(ssum, 2);
      ssum += __shfl_xor(ssum, 4);
      ssum += __shfl_xor(ssum, 8);
      if (r16 == 0) {
        stats[wr*128 + mi*16 + g*4 + j][wcol] = make_float2(vmax, ssum);
      }
    }
  }
  __syncthreads();
  if (tid < 256) {
    float2 a0 = stats[tid][0], a1 = stats[tid][1], a2 = stats[tid][2], a3 = stats[tid][3];
    float M = fmaxf(fmaxf(a0.x, a1.x), fmaxf(a2.x, a3.x));
    float S = a0.y * __expf(a0.x - M) + a1.y * __expf(a1.x - M)
            + a2.y * __expf(a2.x - M) + a3.y * __expf(a3.x - M);
    partials[(long long)(bm0 + tid) * NT + blockIdx.y] = make_float2(M, S);
  }
}

// ---------------- per-row logsumexp + fused target-logit dot --------------------
__global__ void lse_kernel(const float2* __restrict__ partials,
                           const float* __restrict__ x,
                           const float* __restrict__ W,
                           const int* __restrict__ y,
                           float* __restrict__ row_nll) {
  const int n = blockIdx.x * 4 + (threadIdx.x >> 6);   // 1024 blocks x 4 waves
  const int l = threadIdx.x & 63;
  const float2* pr = partials + (long long)n * NT;
  float M = -INFINITY, S = 0.f;
  for (int t = l; t < NT; t += 64) {
    float2 p = pr[t];
    float nM = fmaxf(M, p.x);
    S = S * __expf(M - nM) + p.y * __expf(p.x - nM);
    M = nM;
  }
  // fp32 dot(x_n, W_{y[n]}) on the same wave (float4, coalesced)
  const float4* xr = (const float4*)(x + ((long long)n << 10));
  const float4* wv = (const float4*)(W + ((long long)y[n] << 10));
  float dot = 0.f;
  #pragma unroll
  for (int i = 0; i < 4; ++i) {
    float4 a = xr[l + 64*i];
    float4 b = wv[l + 64*i];
    dot = fmaf(a.x, b.x, fmaf(a.y, b.y, fmaf(a.z, b.z, fmaf(a.w, b.w, dot))));
  }
  #pragma unroll
  for (int off = 1; off < 64; off <<= 1) {
    float Mo = __shfl_xor(M, off);
    float So = __shfl_xor(S, off);
    float nM = fmaxf(M, Mo);
    S = S * __expf(M - nM) + So * __expf(Mo - nM);
    M = nM;
    dot += __shfl_xor(dot, off);
  }
  if (l == 0) row_nll[n] = (M + logf(S)) - dot;
}

__global__ void mean_kernel(const float* __restrict__ row_nll, float* __restrict__ out) {
  __shared__ float red[4];
  float s = 0.f;
  for (int i = threadIdx.x; i < N_NODES; i += 256) s += row_nll[i];
  #pragma unroll
  for (int m = 32; m; m >>= 1) s += __shfl_xor(s, m, 64);
  if ((threadIdx.x & 63) == 0) red[threadIdx.x >> 6] = s;
  __syncthreads();
  if (threadIdx.x == 0) out[0] = (red[0] + red[1] + red[2] + red[3]) * (1.0f / N_NODES);
}

// ---------------- launcher ------------------------------------------------------
extern "C" void kernel_launch(void* const* d_in, const int* in_sizes, int n_in,
                              void* d_out, int out_size, void* d_ws, size_t ws_size,
                              hipStream_t stream) {
  const float* x = (const float*)d_in[0];
  const float* W = (const float*)d_in[1];
  const int*   y = (const int*)d_in[2];
  float* out = (float*)d_out;

  // ws layout (256B-aligned), total 118,161,408 bytes
  char* ws = (char*)d_ws;
  unsigned short* Wb = (unsigned short*)ws;                 // VPAD*D*2 = 103,284,736
  unsigned short* Xb = (unsigned short*)(ws + 103284736);   // N*D*2    =   8,388,608
  float2* partials   = (float2*)(ws + 111673344);           // N*NT*8   =   6,455,296
  float* logit_y     = (float*)(ws + 118128640);            // (unused, kept for layout)
  float* row_nll     = (float*)(ws + 118145024);            // N*4
  (void)logit_y;

  hipLaunchKernelGGL(cvt_w_kernel, dim3(2048), dim3(256), 0, stream, W, Wb);
  hipLaunchKernelGGL(cvt_x_kernel, dim3(N_NODES * (D_EMB / 8) / 256), dim3(256), 0, stream, x, Xb);
  hipLaunchKernelGGL(gemm_stats_kernel, dim3(16, NT), dim3(512), 0, stream, Xb, Wb, partials);
  hipLaunchKernelGGL(lse_kernel, dim3(N_NODES / 4), dim3(256), 0, stream, partials, x, W, y, row_nll);
  hipLaunchKernelGGL(mean_kernel, dim3(1), dim3(256), 0, stream, row_nll, out);
}